// Round 9
// baseline (55.592 us; speedup 1.0000x reference)
//
#include <hip/hip_runtime.h>
#include <hip/hip_bf16.h>

typedef __attribute__((ext_vector_type(8))) short bf16x8;
typedef __attribute__((ext_vector_type(16))) float f32x16;

#define DHEAD 64
#define L_SEQ 2048
// softmax scale 1/8 folded with log2(e): exp(x/8) == exp2(x*QSCALE)
#define QSCALE (0.125f * 1.44269504088896340736f)

union U4S8 { uint4 u; bf16x8 s; };

// Single-instruction f32x2 -> bf16x2 pack (RNE); no builtin on gfx950.
__device__ __forceinline__ unsigned pk2(float a, float b) {
    unsigned r;
    asm("v_cvt_pk_bf16_f32 %0, %1, %2" : "=v"(r) : "v"(a), "v"(b));
    return r;
}

__device__ __forceinline__ float fexp2(float x) {
#if __has_builtin(__builtin_amdgcn_exp2f)
    return __builtin_amdgcn_exp2f(x);
#else
    return __expf(x * 0.69314718055994530942f);
#endif
}

// Depth-4 trees, constant-index only (rule #20: runtime-indexing p -> scratch).
#define MAX16(P) fmaxf(fmaxf(fmaxf(fmaxf(P[0],P[1]),fmaxf(P[2],P[3])),          \
                             fmaxf(fmaxf(P[4],P[5]),fmaxf(P[6],P[7]))),         \
                       fmaxf(fmaxf(fmaxf(P[8],P[9]),fmaxf(P[10],P[11])),        \
                             fmaxf(fmaxf(P[12],P[13]),fmaxf(P[14],P[15]))))
#define SUM16(P) ((((P[0]+P[1])+(P[2]+P[3]))+((P[4]+P[5])+(P[6]+P[7])))         \
                + (((P[8]+P[9])+(P[10]+P[11]))+((P[12]+P[13])+(P[14]+P[15]))))

// Schedule: 256 blocks x 8 waves, 1 block/CU (128KB LDS). Block (bh, pr)
// processes q-tiles {pr, 15-pr} SEQUENTIALLY; within a q-tile the two
// 4-wave groups take even/odd 128-key kv tiles (one 256-key pair staged
// per phase, double-buffered). Total phases = ceil((pr+1)/2)+ceil((16-pr)/2)
// == 9 for ALL pr -> every CU runs the same duration: zero tail.
//
// LDS chunk map sB[buf][ch][slot] (16B slots, all ds ops chunk_base+lane*16):
//   ch  0..15: K tile0   16..31: K tile1   32..47: V tile0   48..63: V tile1
//   K chunk kb*4+kc slot l: K[kb*32+(l&31)][kc*16+8*(l>>5)+j]
//   V chunk kc*2+dt slot l: V[kc*16+8*(l>>5)+j][dt*32+(l&31)]

__global__ __launch_bounds__(512, 2)
void fattn_kernel(const float* __restrict__ Qg, const float* __restrict__ Kg,
                  const float* __restrict__ Vg, float* __restrict__ Og) {
    __shared__ uint4 sB[2][64][64];

    const int tid  = threadIdx.x;
    const int lane = tid & 63;
    const int w    = tid >> 6;     // 0..7
    const int grp  = w >> 2;       // kv parity group (0: even tiles, 1: odd)
    const int wq   = w & 3;        // 32-row q sub-tile within the 128-row q-tile
    const int hi   = lane >> 5;
    const int c    = lane & 31;

    // 256 blocks = 8 xcd x 4 bh x 8 pairs (same-bh blocks share an XCD's L2)
    const int id  = blockIdx.x;
    const int bh  = (id & 7) + 8 * ((id >> 3) & 3);
    const int pr  = id >> 5;                  // 0..7
    const int T0  = pr, T1 = 15 - pr;
    const int ph0 = (T0 + 2) >> 1;            // phases for q-tile 0
    // total phases == 9 for all pr

    const size_t base = (size_t)bh * L_SEQ * DHEAD;

    // ---- Q fragments (B-operand), scale folded; reloaded per q-tile ----
    bf16x8 qf[4];
    auto loadQ = [&](int T) {
        const float* Qrow = Qg + base + (size_t)(T * 128 + wq * 32 + c) * DHEAD;
        #pragma unroll
        for (int kc = 0; kc < 4; ++kc) {
            float4 aa = *(const float4*)(Qrow + kc * 16 + hi * 8);
            float4 bb = *(const float4*)(Qrow + kc * 16 + hi * 8 + 4);
            U4S8 t;
            t.u = make_uint4(pk2(aa.x * QSCALE, aa.y * QSCALE),
                             pk2(aa.z * QSCALE, aa.w * QSCALE),
                             pk2(bb.x * QSCALE, bb.y * QSCALE),
                             pk2(bb.z * QSCALE, bb.w * QSCALE));
            qf[kc] = t.s;
        }
    };

    // ---- staging (512 threads stage one 256-key pair = 64KB/phase) ----
    const float* Kpb = Kg + base + (size_t)(32 * w + c) * DHEAD + 32 * hi;
    const float* Vpb = Vg + base + (size_t)(32 * w + 16 * hi) * DHEAD + c;

    float4 rk[8];
    float  rv[32];

    auto load_pair = [&](int jp) {           // jp = pair index (256 keys each)
        const float* Kp = Kpb + (size_t)jp * 256 * DHEAD;
        #pragma unroll
        for (int t = 0; t < 8; ++t) rk[t] = *(const float4*)(Kp + 4 * t);
        const float* Vp = Vpb + (size_t)jp * 256 * DHEAD;
        #pragma unroll
        for (int j = 0; j < 16; ++j) {
            rv[j]      = Vp[j * DHEAD];
            rv[16 + j] = Vp[j * DHEAD + 32];
        }
    };

    auto write_pair = [&](int nb) {
        #pragma unroll
        for (int q = 0; q < 2; ++q)
            #pragma unroll
            for (int hh = 0; hh < 2; ++hh) {
                const float4 r0 = rk[4 * q + 2 * hh], r1 = rk[4 * q + 2 * hh + 1];
                sB[nb][grp * 16 + wq * 4 + 2 * hi + q][hh * 32 + c] =
                    make_uint4(pk2(r0.x, r0.y), pk2(r0.z, r0.w),
                               pk2(r1.x, r1.y), pk2(r1.z, r1.w));
            }
        #pragma unroll
        for (int dt = 0; dt < 2; ++dt)
            #pragma unroll
            for (int hh = 0; hh < 2; ++hh) {
                const int b = 16 * dt + 8 * hh;
                sB[nb][32 + grp * 16 + (2 * wq + hi) * 2 + dt][hh * 32 + c] =
                    make_uint4(pk2(rv[b + 0], rv[b + 1]), pk2(rv[b + 2], rv[b + 3]),
                               pk2(rv[b + 4], rv[b + 5]), pk2(rv[b + 6], rv[b + 7]));
            }
    };

    f32x16 o0 = {0,0,0,0,0,0,0,0,0,0,0,0,0,0,0,0};
    f32x16 o1 = o0;
    float m_r = -1e30f, l_r = 0.f;

    // exact online-softmax merge of the two groups' states, store, reset.
    // scratch = dead LDS buffer; stride 35 f32 -> 2-way bank alias (free).
    auto merge_store_reset = [&](int T, int dead) {
        float* scr = (float*)&sB[dead][0][0];
        const int sidx = (wq * 64 + lane) * 35;
        if (grp == 1) {
            #pragma unroll
            for (int r = 0; r < 16; ++r) {
                scr[sidx + r]      = o0[r];
                scr[sidx + 16 + r] = o1[r];
            }
            scr[sidx + 32] = m_r;
            scr[sidx + 33] = l_r;
        }
        __syncthreads();
        if (grp == 0) {
            const float mO = scr[sidx + 32], lO = scr[sidx + 33];
            const float mN = fmaxf(m_r, mO);
            const float aE = fexp2(m_r - mN), aO = fexp2(mO - mN);
            const float lN = aE * l_r + aO * lO;
            const float linv = 1.f / lN;
            float* Op = Og + base;
            const int q0 = T * 128 + wq * 32;
            #pragma unroll
            for (int r = 0; r < 16; ++r) {
                const int   cr = (r & 3) + 8 * (r >> 2) + 4 * hi;
                const float bE = __shfl(aE, cr), bO = __shfl(aO, cr);
                const float bl = __shfl(linv, cr);
                const int   row = q0 + cr;
                Op[(size_t)row * DHEAD + c]      = (bE * o0[r] + bO * scr[sidx + r]) * bl;
                Op[(size_t)row * DHEAD + 32 + c] = (bE * o1[r] + bO * scr[sidx + 16 + r]) * bl;
            }
        }
        __syncthreads();
        #pragma unroll
        for (int r = 0; r < 16; ++r) { o0[r] = 0.f; o1[r] = 0.f; }
        m_r = -1e30f; l_r = 0.f;
    };

    loadQ(T0);
    load_pair(0);
    write_pair(0);
    __syncthreads();
    int buf = 0;

    for (int ph = 0; ph < 9; ++ph) {
        const bool inB = (ph >= ph0);
        const int  T   = inB ? T1 : T0;
        const int  jp  = inB ? ph - ph0 : ph;
        const bool pf  = (ph + 1 < 9);
        if (pf) load_pair((ph + 1 >= ph0) ? ph + 1 - ph0 : ph + 1);  // issue-early (T14)

        if (ph == ph0) {                      // q-tile boundary: finish tile T0
            merge_store_reset(T0, buf ^ 1);   // scratch = dead buffer
            loadQ(T1);
        }

        const int kt = 2 * jp + grp;          // this group's 128-key tile
        if (kt <= T) {
            const bool diag = (kt == T);
            const int  nkb  = diag ? (wq + 1) : 4;

            float p[4][16];

            // ---- S^T = K * Q^T ----
            __builtin_amdgcn_s_setprio(1);
            #pragma unroll
            for (int kb = 0; kb < 4; ++kb) {
                if (kb < nkb) {
                    f32x16 s = {0,0,0,0,0,0,0,0,0,0,0,0,0,0,0,0};
                    #pragma unroll
                    for (int kc = 0; kc < 4; ++kc) {
                        U4S8 t; t.u = sB[buf][grp * 16 + kb * 4 + kc][lane];
                        s = __builtin_amdgcn_mfma_f32_32x32x16_bf16(t.s, qf[kc], s, 0, 0, 0);
                    }
                    #pragma unroll
                    for (int r = 0; r < 16; ++r) p[kb][r] = s[r];
                }
            }
            __builtin_amdgcn_s_setprio(0);

            // diagonal mask: compile-time kb index, runtime CONDITION only
            #pragma unroll
            for (int kb = 0; kb < 4; ++kb) {
                if (diag && kb == wq) {
                    #pragma unroll
                    for (int r = 0; r < 16; ++r) {
                        const int kk = (r & 3) + 8 * (r >> 2) + 4 * hi;
                        if (kk > c) p[kb][r] = -1e30f;
                    }
                }
            }

            // ---- online softmax (depth-4 trees, exp2 domain) ----
            float mx = MAX16(p[0]);
            if (nkb > 1) {
                float mxb = (nkb > 2) ? fmaxf(MAX16(p[1]),
                                              (nkb > 3) ? fmaxf(MAX16(p[2]), MAX16(p[3]))
                                                        : MAX16(p[2]))
                                      : MAX16(p[1]);
                mx = fmaxf(mx, mxb);
            }
            mx = fmaxf(mx, __shfl_xor(mx, 32));

            if (__any(mx > m_r + 8.f)) {    // defer-max (T13)
                const float mn    = fmaxf(m_r, mx);
                const float alpha = fexp2(m_r - mn);
                m_r  = mn;
                l_r *= alpha;
                #pragma unroll
                for (int r = 0; r < 16; ++r) {
                    const float ab = __shfl(alpha, (r & 3) + 8 * (r >> 2) + 4 * hi);
                    o0[r] *= ab; o1[r] *= ab;
                }
            }

            #pragma unroll
            for (int kb = 0; kb < 4; ++kb) {
                if (kb < nkb) {
                    #pragma unroll
                    for (int r = 0; r < 16; ++r) p[kb][r] = fexp2(p[kb][r] - m_r);
                }
            }
            float rs = SUM16(p[0]);
            if (nkb > 1) {
                float rsb = (nkb > 2) ? ((nkb > 3) ? (SUM16(p[1]) + (SUM16(p[2]) + SUM16(p[3])))
                                                   : (SUM16(p[1]) + SUM16(p[2])))
                                      : SUM16(p[1]);
                rs += rsb;
            }
            rs += __shfl_xor(rs, 32);
            l_r += rs;

            // ---- P -> A-frags via v_permlane32_swap_b32 + O += P V ----
            __builtin_amdgcn_s_setprio(1);
            #pragma unroll
            for (int kc = 0; kc < 8; ++kc) {
                if (kc < 2 * nkb) {
                    const int kb = kc >> 1, bs = (kc & 1) * 8;
                    unsigned a0 = pk2(p[kb][bs + 0], p[kb][bs + 1]);
                    unsigned a1 = pk2(p[kb][bs + 2], p[kb][bs + 3]);
                    unsigned b0 = pk2(p[kb][bs + 4], p[kb][bs + 5]);
                    unsigned b1 = pk2(p[kb][bs + 6], p[kb][bs + 7]);
                    asm("v_permlane32_swap_b32 %0, %1" : "+v"(a0), "+v"(b0));
                    asm("v_permlane32_swap_b32 %0, %1" : "+v"(a1), "+v"(b1));
                    U4S8 t;
                    t.u = make_uint4(a0, a1, b0, b1);
                    U4S8 tv0; tv0.u = sB[buf][32 + grp * 16 + kc * 2][lane];
                    o0 = __builtin_amdgcn_mfma_f32_32x32x16_bf16(t.s, tv0.s, o0, 0, 0, 0);
                    U4S8 tv1; tv1.u = sB[buf][32 + grp * 16 + kc * 2 + 1][lane];
                    o1 = __builtin_amdgcn_mfma_f32_32x32x16_bf16(t.s, tv1.s, o1, 0, 0, 0);
                }
            }
            __builtin_amdgcn_s_setprio(0);
        }

        if (pf) write_pair(buf ^ 1);        // write-late (loads drained under compute)
        __syncthreads();
        buf ^= 1;
    }

    merge_store_reset(T1, buf);             // both buffers dead now
}

extern "C" void kernel_launch(void* const* d_in, const int* in_sizes, int n_in,
                              void* d_out, int out_size, void* d_ws, size_t ws_size,
                              hipStream_t stream) {
    const float* Q = (const float*)d_in[0];
    const float* K = (const float*)d_in[1];
    const float* V = (const float*)d_in[2];
    float* O = (float*)d_out;
    fattn_kernel<<<dim3(256), dim3(512), 0, stream>>>(Q, K, V, O);
}